// Round 1
// baseline (589.276 us; speedup 1.0000x reference)
//
#include <hip/hip_runtime.h>

// Problem constants (match reference file)
#define N_NODES 2000000
#define N_EDGES 32000000
#define N_OUT   400000   // N_NODES / 5

// Edge scatter: for each edge (src, dst), if dst % 5 == 0 accumulate x[src]
// into agg[dst/5]. Only those nodes survive the final reshape(-1,5)[:,0].
// dst is read vectorized (int4, 16B/thread); src and x[src] loaded only when
// needed. w_conv is folded into the epilogue (segment_sum is linear).
__global__ __launch_bounds__(256) void gcn_edge_scatter(
    const int* __restrict__ src,
    const int* __restrict__ dst,
    const float* __restrict__ x,
    float* __restrict__ agg)
{
    const long long base = ((long long)blockIdx.x * blockDim.x + threadIdx.x) * 4;
    if (base >= N_EDGES) return;
    const int4 d4 = *reinterpret_cast<const int4*>(dst + base);
    const int dd[4] = {d4.x, d4.y, d4.z, d4.w};
#pragma unroll
    for (int k = 0; k < 4; ++k) {
        const int d = dd[k];
        if (d % 5 == 0) {
            const int s = src[base + k];
            atomicAdd(&agg[d / 5], x[s]);
        }
    }
}

// Epilogue: agg_node = agg_raw * w_conv + b_conv, then the 2->4->1 MLP with
// both input columns identical: t_j = relu(agg*(w1[0,j]+w1[1,j]) + b1[j]),
// out = sum_j t_j * w2[j] + b2.
__global__ __launch_bounds__(256) void gcn_epilogue(
    const float* __restrict__ agg,
    const float* __restrict__ w_conv,
    const float* __restrict__ b_conv,
    const float* __restrict__ w1,   // [2,4] row-major
    const float* __restrict__ b1,   // [4]
    const float* __restrict__ w2,   // [4,1]
    const float* __restrict__ b2,   // [1]
    float* __restrict__ out)
{
    const int i = blockIdx.x * blockDim.x + threadIdx.x;
    if (i >= N_OUT) return;
    const float wc = w_conv[0];
    const float bc = b_conv[0];
    const float a = agg[i] * wc + bc;
    float r = b2[0];
#pragma unroll
    for (int j = 0; j < 4; ++j) {
        float t = fmaf(a, w1[j] + w1[4 + j], b1[j]);
        t = fmaxf(t, 0.0f);
        r = fmaf(t, w2[j], r);
    }
    out[i] = r;
}

extern "C" void kernel_launch(void* const* d_in, const int* in_sizes, int n_in,
                              void* d_out, int out_size, void* d_ws, size_t ws_size,
                              hipStream_t stream) {
    const float* x      = (const float*)d_in[0];
    const int*   ei     = (const int*)  d_in[1];  // [2, N_EDGES]: src row then dst row
    const float* w_conv = (const float*)d_in[2];
    const float* b_conv = (const float*)d_in[3];
    const float* w1     = (const float*)d_in[4];
    const float* b1     = (const float*)d_in[5];
    const float* w2     = (const float*)d_in[6];
    const float* b2     = (const float*)d_in[7];
    float* out = (float*)d_out;
    float* agg = (float*)d_ws;   // N_OUT floats of scratch (harness poisons -> zero it)

    hipMemsetAsync(agg, 0, (size_t)N_OUT * sizeof(float), stream);

    // 32M edges / 4 per thread = 8M threads = 31250 blocks of 256 (exact).
    gcn_edge_scatter<<<31250, 256, 0, stream>>>(ei, ei + N_EDGES, x, agg);

    gcn_epilogue<<<(N_OUT + 255) / 256, 256, 0, stream>>>(
        agg, w_conv, b_conv, w1, b1, w2, b2, out);
}